// Round 7
// baseline (224.297 us; speedup 1.0000x reference)
//
#include <hip/hip_runtime.h>
#include <math.h>

#define LATENT 1024
#define QDIM 256
#define NW 196608           // LATENT * CPG * K
#define BI 128
#define BC 32
#define TT 50
#define REGIONS 36
#define NGROUPS 16
#define CPG 64
#define NEG 0.1f

typedef __attribute__((ext_vector_type(8))) short short8;
typedef __attribute__((ext_vector_type(16))) float f32x16;

__device__ __forceinline__ float leakyf(float x){ return x > 0.f ? x : NEG * x; }

__device__ __forceinline__ unsigned short f2bf(float x){
    union { float f; unsigned int u; } v; v.f = x;
    unsigned int r = v.u + 0x7FFFu + ((v.u >> 16) & 1u);   // RNE
    return (unsigned short)(r >> 16);
}

// ---------------------------------------------------------------------------
// Kernel 1a: masked mean + gate(pre-scaled by 1/36) + ||cap_repr||.
// ---------------------------------------------------------------------------
__global__ __launch_bounds__(256) void cap_mean_kernel(
    const float* __restrict__ cap_embed, const int* __restrict__ lens,
    float* __restrict__ cap_repr, float* __restrict__ cap_act,
    float* __restrict__ norm_capr)
{
    const int n = blockIdx.x;
    const int len = lens[n];
    const float invl = 1.f / (float)len;
    const int c4 = threadIdx.x;
    const float* base = cap_embed + (size_t)n * TT * LATENT + c4 * 4;
    float4 s = {0.f, 0.f, 0.f, 0.f};
    for (int t = 0; t < len; ++t) {
        const float4 v = *reinterpret_cast<const float4*>(base + (size_t)t * LATENT);
        s.x += v.x; s.y += v.y; s.z += v.z; s.w += v.w;
    }
    float4 m = {s.x * invl, s.y * invl, s.z * invl, s.w * invl};
    *reinterpret_cast<float4*>(cap_repr + n * LATENT + c4 * 4) = m;
    const float sc = 1.f / 36.f;
    float4 a = {leakyf(m.x) * sc, leakyf(m.y) * sc, leakyf(m.z) * sc, leakyf(m.w) * sc};
    *reinterpret_cast<float4*>(cap_act + n * LATENT + c4 * 4) = a;
    float ss = m.x*m.x + m.y*m.y + m.z*m.z + m.w*m.w;
    #pragma unroll
    for (int off = 32; off; off >>= 1) ss += __shfl_xor(ss, off);
    __shared__ float red4[4];
    if ((threadIdx.x & 63) == 0) red4[threadIdx.x >> 6] = ss;
    __syncthreads();
    if (threadIdx.x == 0) norm_capr[n] = sqrtf(red4[0] + red4[1] + red4[2] + red4[3]);
}

// ---------------------------------------------------------------------------
// Kernel 1b: qT[r][n] = cap_repr[n,:] @ red_w[:,r] + red_b[r]
// ---------------------------------------------------------------------------
__global__ __launch_bounds__(256) void q_kernel(
    const float* __restrict__ cap_repr, const float* __restrict__ red_w,
    const float* __restrict__ red_b, float* __restrict__ qT)
{
    const int cg = blockIdx.x, n = blockIdx.y;
    const int col = threadIdx.x & 31, ks = threadIdx.x >> 5;
    const float* cr = cap_repr + n * LATENT;
    float p = 0.f;
    const int r0 = ks * 128;
    for (int r = r0; r < r0 + 128; ++r)
        p = fmaf(cr[r], red_w[(size_t)r * QDIM + cg * 32 + col], p);
    __shared__ float part[256];
    part[threadIdx.x] = p;
    __syncthreads();
    if (threadIdx.x < 32) {
        float s = red_b[cg * 32 + col];
        #pragma unroll
        for (int k = 0; k < 8; ++k) s += part[k * 32 + col];
        qT[(cg * 32 + col) * 32 + n] = s;
    }
}

// ---------------------------------------------------------------------------
// Kernel 2: wgen7 — 1 col/thread, 1024 blocks x 192 thr. q staged in LDS
// (broadcast ds_reads, no K$ thrash); LDS aliased for the softmax transpose
// so total stays 32KB (4 blocks/CU). Frag-major bf16 output Wp2F.
// ---------------------------------------------------------------------------
__global__ __launch_bounds__(192) void wgen7_kernel(
    const float* __restrict__ qT, const float* __restrict__ proj_w,
    const float* __restrict__ proj_b, unsigned short* __restrict__ Wp2F)
{
    __shared__ float smem[8192];          // 32KB: qs[256*32] then L[192*33]
    for (int idx = threadIdx.x; idx < 2048; idx += 192)
        *reinterpret_cast<float4*>(smem + idx * 4) =
            *reinterpret_cast<const float4*>(qT + idx * 4);
    __syncthreads();

    const int tid = threadIdx.x;
    const int g = blockIdx.x >> 6, o = blockIdx.x & 63;
    const int col = (g * 64 + o) * 192 + tid;
    float acc[32];
    #pragma unroll
    for (int n2 = 0; n2 < 32; ++n2) acc[n2] = 0.f;
    #pragma unroll 4
    for (int r = 0; r < QDIM; ++r) {
        const float w = proj_w[(size_t)r * NW + col];
        const float* qr = smem + r * 32;      // wave-uniform -> LDS broadcast
        #pragma unroll
        for (int nb = 0; nb < 8; ++nb) {
            const float4 qv = *reinterpret_cast<const float4*>(qr + nb * 4);
            acc[nb*4+0] = fmaf(w, qv.x, acc[nb*4+0]);
            acc[nb*4+1] = fmaf(w, qv.y, acc[nb*4+1]);
            acc[nb*4+2] = fmaf(w, qv.z, acc[nb*4+2]);
            acc[nb*4+3] = fmaf(w, qv.w, acc[nb*4+3]);
        }
    }
    const float b = proj_b[col];
    __syncthreads();                      // all reads of qs done; alias as L
    float* L = smem;                      // [col_in_block][n], stride 33 (6336 floats)
    #pragma unroll
    for (int n2 = 0; n2 < 32; ++n2) L[tid * 33 + n2] = acc[n2] + b;
    __syncthreads();

    const int nt = o >> 5, lrow = o & 31;
    for (int idx = tid; idx < 2048; idx += 192) {
        const int n = idx & 31, i = idx >> 5;      // i < 64
        const int c = i * 3;
        const float x0 = L[c * 33 + n], x1 = L[(c+1)*33 + n], x2 = L[(c+2)*33 + n];
        const float m = fmaxf(fmaxf(x0, x1), x2);
        const float e0 = expf(x0 - m), e1 = expf(x1 - m), e2 = expf(x2 - m);
        const float inv = 1.f / (e0 + e1 + e2);
        const int ks = i >> 4, khalf = (i >> 3) & 1, j = i & 7;
        const size_t base = (size_t)(n * 16 + g) * 12288
                          + (size_t)(nt * 4 + ks) * 512
                          + khalf * 256 + lrow * 8 + j;
        Wp2F[base]        = f2bf(e0 * inv);   // k=0
        Wp2F[base + 4096] = f2bf(e1 * inv);   // k=1 (+8 frags)
        Wp2F[base + 8192] = f2bf(e2 * inv);   // k=2
    }
}

// ---------------------------------------------------------------------------
// Kernel 3: conv5 — 576 thr = 9 thin waves, 1 M-tile (32 rows) per wave.
// A-frags (12/wave) cached in registers for the whole caption loop (no LDS
// A-reads). B double-buffered in LDS (aliases dead A-staging buffer),
// reg-staged prefetch issued before MFMAs. 1 barrier/caption via Sw dbuf.
// grid = (g=16, bt=16, nq=2), 16 captions per block.
// ---------------------------------------------------------------------------
__global__ __launch_bounds__(576, 3) void conv5_kernel(
    const float* __restrict__ img_embed, const unsigned short* __restrict__ Wp2F,
    const float* __restrict__ cap_repr, const float* __restrict__ cap_act,
    float* __restrict__ part_dot, float* __restrict__ part_ss)
{
    const int g = blockIdx.x, bt = blockIdx.y, nq = blockIdx.z;
    const int b0 = bt * 8;
    __shared__ int4 BsmV[3072];            // 48KB: A-staging, then B dbuf 2x24KB
    char* BsmRaw = (char*)BsmV;
    __shared__ float Sw[2][9][2][64];      // 9KB, double-buffered partials
    const int tid = threadIdx.x;
    const int wv = tid >> 6, lane = tid & 63;
    const int lrow = lane & 31, khalf = lane >> 5;
    const int ioff = khalf * 16;

    // ---- stage A (8 images, swizzled, fused f32->bf16) ----
    const float* imgG = img_embed + (size_t)b0 * 36 * 1024 + g * 64;
    for (int idx = tid; idx < 2304; idx += 576) {
        const int row_img = idx >> 3, ch = idx & 7;
        const int bbs = row_img / 36;
        const int l = row_img - bbs * 36;
        const float* src = imgG + (size_t)row_img * 1024 + ch * 8;
        const float4 u = *reinterpret_cast<const float4*>(src);
        const float4 v = *reinterpret_cast<const float4*>(src + 4);
        unsigned short r8[8];
        r8[0]=f2bf(u.x); r8[1]=f2bf(u.y); r8[2]=f2bf(u.z); r8[3]=f2bf(u.w);
        r8[4]=f2bf(v.x); r8[5]=f2bf(v.y); r8[6]=f2bf(v.z); r8[7]=f2bf(v.w);
        const int arow = bbs * 38 + l + 1;
        const int byte = (arow * 128 + ch * 16) ^ ((arow & 7) << 4);
        *reinterpret_cast<int4*>(BsmRaw + byte) = *reinterpret_cast<const int4*>(r8);
    }
    if (tid < 128) {   // zero pad rows (pos 0 and 37 per image)
        const int rr = tid >> 3, ch = tid & 7;
        const int arow = (rr >> 1) * 38 + (rr & 1) * 37;
        const int byte = (arow * 128 + ch * 16) ^ ((arow & 7) << 4);
        int4 z; z.x = 0; z.y = 0; z.z = 0; z.w = 0;
        *reinterpret_cast<int4*>(BsmRaw + byte) = z;
    }
    __syncthreads();

    // ---- A-frags to registers: wave wv owns rows [32wv, 32wv+32) ----
    const int rg = wv * 32 + lrow;
    const int bbr = rg / 36;
    const int abase = bbr * 38 + (rg - bbr * 36);
    short8 afr[3][4];
    #pragma unroll
    for (int k = 0; k < 3; ++k)
        #pragma unroll
        for (int ks = 0; ks < 4; ++ks) {
            const int arow = abase + k;
            const int byte = (arow * 128 + ks * 32 + ioff) ^ ((arow & 7) << 4);
            afr[k][ks] = *reinterpret_cast<const short8*>(BsmRaw + byte);
        }
    const int rbase = wv * 32;
    const int bfirst = rbase / 36;
    const int bsplit = (bfirst + 1) * 36 - rbase;   // tile-rows >= bsplit -> img bfirst+1
    __syncthreads();   // all A reads done; BsmRaw becomes B double-buffer

    // ---- B prologue: stage caption n0 into buf0 ----
    const int n0 = nq * 16;
    int4 st0, st1, st2;
    {
        const unsigned short* WF = Wp2F + (size_t)(n0 * 16 + g) * 12288;
        st0 = *reinterpret_cast<const int4*>(WF + (size_t)tid * 8);
        st1 = *reinterpret_cast<const int4*>(WF + (size_t)(tid + 576) * 8);
        if (tid < 384) st2 = *reinterpret_cast<const int4*>(WF + (size_t)(tid + 1152) * 8);
        *reinterpret_cast<int4*>(BsmRaw + (size_t)tid * 16) = st0;
        *reinterpret_cast<int4*>(BsmRaw + (size_t)(tid + 576) * 16) = st1;
        if (tid < 384) *reinterpret_cast<int4*>(BsmRaw + (size_t)(tid + 1152) * 16) = st2;
    }
    __syncthreads();

    for (int ni = 0; ni < 16; ++ni) {
        const int n = n0 + ni;
        char* Bcur = BsmRaw + (size_t)(ni & 1) * 24576;
        char* Bnxt = BsmRaw + (size_t)((ni + 1) & 1) * 24576;

        if (ni < 15) {   // issue next caption's loads (latency hidden by MFMA)
            const unsigned short* WF = Wp2F + (size_t)((n + 1) * 16 + g) * 12288;
            st0 = *reinterpret_cast<const int4*>(WF + (size_t)tid * 8);
            st1 = *reinterpret_cast<const int4*>(WF + (size_t)(tid + 576) * 8);
            if (tid < 384) st2 = *reinterpret_cast<const int4*>(WF + (size_t)(tid + 1152) * 8);
        }

        f32x16 acc0 = {}, acc1 = {};
        #pragma unroll
        for (int k = 0; k < 3; ++k) {
            #pragma unroll
            for (int ks = 0; ks < 4; ++ks) {
                const char* fb = Bcur + k * 8192 + ks * 1024 + (size_t)lane * 16;
                const short8 bf0 = *reinterpret_cast<const short8*>(fb);
                const short8 bf1 = *reinterpret_cast<const short8*>(fb + 4096);
                acc0 = __builtin_amdgcn_mfma_f32_32x32x16_bf16(afr[k][ks], bf0, acc0, 0, 0, 0);
                acc1 = __builtin_amdgcn_mfma_f32_32x32x16_bf16(afr[k][ks], bf1, acc1, 0, 0, 0);
            }
        }

        if (ni < 15) {   // write staged B into inactive buffer
            *reinterpret_cast<int4*>(Bnxt + (size_t)tid * 16) = st0;
            *reinterpret_cast<int4*>(Bnxt + (size_t)(tid + 576) * 16) = st1;
            if (tid < 384) *reinterpret_cast<int4*>(Bnxt + (size_t)(tid + 1152) * 16) = st2;
        }

        // epilogue: leaky + per-image column sums -> Sw[ni&1]
        float s0A = 0.f, s0B = 0.f, s1A = 0.f, s1B = 0.f;
        #pragma unroll
        for (int reg = 0; reg < 16; ++reg) {
            const int rit = (reg & 3) + 8 * (reg >> 2) + 4 * khalf;
            const float v0 = leakyf(acc0[reg]);
            const float v1 = leakyf(acc1[reg]);
            if (rit >= bsplit) { s0B += v0; s1B += v1; }
            else               { s0A += v0; s1A += v1; }
        }
        s0A += __shfl_xor(s0A, 32); s0B += __shfl_xor(s0B, 32);
        s1A += __shfl_xor(s1A, 32); s1B += __shfl_xor(s1B, 32);
        const int q = ni & 1;
        if (khalf == 0) {
            Sw[q][wv][0][lrow]      = s0A;
            Sw[q][wv][0][32 + lrow] = s1A;
            if (bsplit < 32) {
                Sw[q][wv][1][lrow]      = s0B;
                Sw[q][wv][1][32 + lrow] = s1B;
            }
        }
        __syncthreads();   // Sw[q] complete; Bnxt staged

        if (tid < 128) {   // gather: img b = waves {b,slot1}+{b+1,slot0} (b>0)
            const int b = tid >> 4, j = tid & 15;
            const float4 ca4 = *reinterpret_cast<const float4*>(&cap_act [n * LATENT + g * CPG + j * 4]);
            const float4 cr4 = *reinterpret_cast<const float4*>(&cap_repr[n * LATENT + g * CPG + j * 4]);
            const float cav[4] = {ca4.x, ca4.y, ca4.z, ca4.w};
            const float crv[4] = {cr4.x, cr4.y, cr4.z, cr4.w};
            float d = 0.f, ss = 0.f;
            #pragma unroll
            for (int u = 0; u < 4; ++u) {
                const int o = j * 4 + u;
                const float S = (b == 0)
                    ? Sw[q][0][0][o] + Sw[q][1][0][o]
                    : Sw[q][b][1][o] + Sw[q][b + 1][0][o];
                const float tmp = S * cav[u];          // cap_act pre-scaled by 1/36
                d = fmaf(tmp, crv[u], d);
                ss = fmaf(tmp, tmp, ss);
            }
            #pragma unroll
            for (int off = 1; off <= 8; off <<= 1) {
                d += __shfl_xor(d, off);
                ss += __shfl_xor(ss, off);
            }
            if (j == 0) {
                part_dot[((size_t)n * BI + b0 + b) * NGROUPS + g] = d;
                part_ss [((size_t)n * BI + b0 + b) * NGROUPS + g] = ss;
            }
        }
    }
}

// ---------------------------------------------------------------------------
// Kernel 4: combine 16 group-partials -> sims[b*32+n]
// ---------------------------------------------------------------------------
__global__ __launch_bounds__(256) void final_kernel(
    const float* __restrict__ part_dot, const float* __restrict__ part_ss,
    const float* __restrict__ norm_capr, float* __restrict__ out)
{
    const int idx = blockIdx.x * 256 + threadIdx.x;   // 4096
    const int n = idx & 31;
    const int b = idx >> 5;
    const size_t base = ((size_t)n * BI + b) * NGROUPS;
    float d = 0.f, s = 0.f;
    #pragma unroll
    for (int g = 0; g < NGROUPS; ++g) { d += part_dot[base + g]; s += part_ss[base + g]; }
    out[b * BC + n] = d / (sqrtf(s) * norm_capr[n]);
}

// ---------------------------------------------------------------------------
extern "C" void kernel_launch(void* const* d_in, const int* in_sizes, int n_in,
                              void* d_out, int out_size, void* d_ws, size_t ws_size,
                              hipStream_t stream) {
    const float* img_embed = (const float*)d_in[0];   // (128, 36, 1024)
    const float* cap_embed = (const float*)d_in[1];   // (32, 50, 1024)
    const int*   lens      = (const int*)  d_in[2];   // (32,)
    const float* red_w     = (const float*)d_in[3];   // (1024, 256)
    const float* red_b     = (const float*)d_in[4];   // (256,)
    const float* proj_w    = (const float*)d_in[5];   // (256, 196608)
    const float* proj_b    = (const float*)d_in[6];   // (196608,)
    float* out = (float*)d_out;                        // (128, 32)

    char* ws = (char*)d_ws;
    unsigned short* Wp2F   = (unsigned short*)(ws);                    // 12,582,912 B
    float* cap_repr  = (float*)(ws + 22020096);                        //    131,072 B
    float* cap_act   = (float*)(ws + 22151168);                        //    131,072 B
    float* qT        = (float*)(ws + 22282240);                        //     32,768 B
    float* norm_capr = (float*)(ws + 22315008);                        //        512 B
    float* part_dot  = (float*)(ws + 22315520);                        //    262,144 B
    float* part_ss   = (float*)(ws + 22577664);                        //    262,144 B

    hipLaunchKernelGGL(cap_mean_kernel, dim3(BC), dim3(256), 0, stream,
                       cap_embed, lens, cap_repr, cap_act, norm_capr);
    hipLaunchKernelGGL(q_kernel, dim3(8, BC), dim3(256), 0, stream,
                       cap_repr, red_w, red_b, qT);
    hipLaunchKernelGGL(wgen7_kernel, dim3(1024), dim3(192), 0, stream,
                       qT, proj_w, proj_b, Wp2F);
    hipLaunchKernelGGL(conv5_kernel, dim3(NGROUPS, 16, 2), dim3(576), 0, stream,
                       img_embed, Wp2F, cap_repr, cap_act, part_dot, part_ss);
    hipLaunchKernelGGL(final_kernel, dim3(16), dim3(256), 0, stream,
                       part_dot, part_ss, norm_capr, out);
}

// Round 8
// 186.536 us; speedup vs baseline: 1.2024x; 1.2024x over previous
//
#include <hip/hip_runtime.h>
#include <math.h>

#define LATENT 1024
#define QDIM 256
#define NW 196608           // LATENT * CPG * K
#define BI 128
#define BC 32
#define TT 50
#define REGIONS 36
#define NGROUPS 16
#define CPG 64
#define NEG 0.1f

typedef __attribute__((ext_vector_type(8))) short short8;
typedef __attribute__((ext_vector_type(16))) float f32x16;

__device__ __forceinline__ float leakyf(float x){ return x > 0.f ? x : NEG * x; }

__device__ __forceinline__ unsigned short f2bf(float x){
    union { float f; unsigned int u; } v; v.f = x;
    unsigned int r = v.u + 0x7FFFu + ((v.u >> 16) & 1u);   // RNE
    return (unsigned short)(r >> 16);
}

// ---------------------------------------------------------------------------
// Kernel 1a: masked mean + gate(pre-scaled by 1/36) + ||cap_repr||.
// ---------------------------------------------------------------------------
__global__ __launch_bounds__(256) void cap_mean_kernel(
    const float* __restrict__ cap_embed, const int* __restrict__ lens,
    float* __restrict__ cap_repr, float* __restrict__ cap_act,
    float* __restrict__ norm_capr)
{
    const int n = blockIdx.x;
    const int len = lens[n];
    const float invl = 1.f / (float)len;
    const int c4 = threadIdx.x;
    const float* base = cap_embed + (size_t)n * TT * LATENT + c4 * 4;
    float4 s = {0.f, 0.f, 0.f, 0.f};
    for (int t = 0; t < len; ++t) {
        const float4 v = *reinterpret_cast<const float4*>(base + (size_t)t * LATENT);
        s.x += v.x; s.y += v.y; s.z += v.z; s.w += v.w;
    }
    float4 m = {s.x * invl, s.y * invl, s.z * invl, s.w * invl};
    *reinterpret_cast<float4*>(cap_repr + n * LATENT + c4 * 4) = m;
    const float sc = 1.f / 36.f;
    float4 a = {leakyf(m.x) * sc, leakyf(m.y) * sc, leakyf(m.z) * sc, leakyf(m.w) * sc};
    *reinterpret_cast<float4*>(cap_act + n * LATENT + c4 * 4) = a;
    float ss = m.x*m.x + m.y*m.y + m.z*m.z + m.w*m.w;
    #pragma unroll
    for (int off = 32; off; off >>= 1) ss += __shfl_xor(ss, off);
    __shared__ float red4[4];
    if ((threadIdx.x & 63) == 0) red4[threadIdx.x >> 6] = ss;
    __syncthreads();
    if (threadIdx.x == 0) norm_capr[n] = sqrtf(red4[0] + red4[1] + red4[2] + red4[3]);
}

// ---------------------------------------------------------------------------
// Kernel 1b: q = cap_repr @ red_w + red_b, packed DIRECTLY into bf16 A-frag
// layout qbfF: elem (r>>4)*512 + ((r>>3)&1)*256 + n*8 + (r&7)  (16KB total)
// ---------------------------------------------------------------------------
__global__ __launch_bounds__(256) void q_kernel(
    const float* __restrict__ cap_repr, const float* __restrict__ red_w,
    const float* __restrict__ red_b, unsigned short* __restrict__ qbfF)
{
    const int cg = blockIdx.x, n = blockIdx.y;
    const int col = threadIdx.x & 31, ks = threadIdx.x >> 5;
    const float* cr = cap_repr + n * LATENT;
    float p = 0.f;
    const int r0 = ks * 128;
    for (int r = r0; r < r0 + 128; ++r)
        p = fmaf(cr[r], red_w[(size_t)r * QDIM + cg * 32 + col], p);
    __shared__ float part[256];
    part[threadIdx.x] = p;
    __syncthreads();
    if (threadIdx.x < 32) {
        float s = red_b[cg * 32 + col];
        #pragma unroll
        for (int k = 0; k < 8; ++k) s += part[k * 32 + col];
        const int r = cg * 32 + col;
        const int elem = (r >> 4) * 512 + ((r >> 3) & 1) * 256 + n * 8 + (r & 7);
        qbfF[elem] = f2bf(s);
    }
}

// ---------------------------------------------------------------------------
// Kernel 2: wgen8 — MFMA W-GEMM. Block = one (g,o) slice (192 cols), 384 thr
// = 6 waves; wave w owns cols [32w,32w+32), all 32 captions, K=256.
// A (q bf16 frags) held in registers (16 frags); B staged per 16-K-step into
// frag-major dbuf LDS (f32->bf16 in flight). Epilogue: bias + softmax(K=3)
// + frag-major bf16 pack (unchanged layout for conv).
// ---------------------------------------------------------------------------
__global__ __launch_bounds__(384) void wgen8_kernel(
    const unsigned short* __restrict__ qbfF, const float* __restrict__ proj_w,
    const float* __restrict__ proj_b, unsigned short* __restrict__ Wp2F)
{
    __shared__ unsigned short Bst[2][3072];   // 2 x 6KB frag-major step tiles
    __shared__ float L[192 * 33];             // logits [col][n]
    const int tid = threadIdx.x;
    const int g = blockIdx.x >> 6, o = blockIdx.x & 63;
    const int colbase = (g * 64 + o) * 192;
    const int wv = tid >> 6, lane = tid & 63;
    const int lrow = lane & 31, khalf = lane >> 5;

    // A-frags: lane l reads 16B at l*16 per step chunk -> coalesced
    short8 afr[16];
    {
        const unsigned short* qp = qbfF + (size_t)lane * 8;
        #pragma unroll
        for (int s = 0; s < 16; ++s)
            afr[s] = *reinterpret_cast<const short8*>(qp + s * 512);
    }

    // staging role: thread = (c4 = 4 cols, rp = r-pair), covers 16r x 192col
    const int c4 = tid % 48;
    const int rp = tid / 48;
    const int c0 = c4 * 4;
    const int kh_w = rp >> 2;
    const int j0 = (rp * 2) & 7;              // even

    float4 A0, A1;
    {
        const float* src = proj_w + (size_t)(rp * 2) * NW + colbase + c0;
        A0 = *reinterpret_cast<const float4*>(src);
        A1 = *reinterpret_cast<const float4*>(src + NW);
    }

    f32x16 acc = {};
    for (int s = 0; s < 16; ++s) {
        __syncthreads();                      // buf (s&1) free (mfma s-2 done)
        unsigned short* Bb = Bst[s & 1];
        {
            const float a0[4] = {A0.x, A0.y, A0.z, A0.w};
            const float a1[4] = {A1.x, A1.y, A1.z, A1.w};
            #pragma unroll
            for (int cc = 0; cc < 4; ++cc) {
                const int col = c0 + cc;
                const unsigned int lo = f2bf(a0[cc]);
                const unsigned int hi = f2bf(a1[cc]);
                const int ei = (col >> 5) * 512 + kh_w * 256 + (col & 31) * 8 + j0;
                *reinterpret_cast<unsigned int*>(&Bb[ei]) = lo | (hi << 16);
            }
        }
        if (s < 15) {                         // issue next step's loads early
            const float* src = proj_w + (size_t)((s + 1) * 16 + rp * 2) * NW + colbase + c0;
            A0 = *reinterpret_cast<const float4*>(src);
            A1 = *reinterpret_cast<const float4*>(src + NW);
        }
        __syncthreads();                      // buf ready
        const short8 bf = *reinterpret_cast<const short8*>(&Bb[wv * 512 + lane * 8]);
        acc = __builtin_amdgcn_mfma_f32_32x32x16_bf16(afr[s], bf, acc, 0, 0, 0);
    }

    // C -> L with bias (C/D: col=lane&31, row n=(reg&3)+8*(reg>>2)+4*khalf)
    const int col_local = wv * 32 + lrow;
    const float pb = proj_b[colbase + col_local];
    #pragma unroll
    for (int reg = 0; reg < 16; ++reg) {
        const int n = (reg & 3) + 8 * (reg >> 2) + 4 * khalf;
        L[col_local * 33 + n] = acc[reg] + pb;
    }
    __syncthreads();

    // softmax over k-triples + frag-major bf16 pack
    const int nt = o >> 5, lrow_o = o & 63 & 31;
    for (int idx = tid; idx < 2048; idx += 384) {
        const int n = idx & 31, i = idx >> 5;     // i < 64
        const int c = i * 3;
        const float x0 = L[c * 33 + n], x1 = L[(c+1)*33 + n], x2 = L[(c+2)*33 + n];
        const float m = fmaxf(fmaxf(x0, x1), x2);
        const float e0 = expf(x0 - m), e1 = expf(x1 - m), e2 = expf(x2 - m);
        const float inv = 1.f / (e0 + e1 + e2);
        const int ks = i >> 4, kh = (i >> 3) & 1, j = i & 7;
        const size_t base = (size_t)(n * 16 + g) * 12288
                          + (size_t)(nt * 4 + ks) * 512
                          + kh * 256 + lrow_o * 8 + j;
        Wp2F[base]        = f2bf(e0 * inv);   // k=0
        Wp2F[base + 4096] = f2bf(e1 * inv);   // k=1 (+8 frags)
        Wp2F[base + 8192] = f2bf(e2 * inv);   // k=2
    }
}

// ---------------------------------------------------------------------------
// Kernel 3: conv5 — 576 thr = 9 thin waves, 1 M-tile (32 rows) per wave.
// A-frags cached in registers; B double-buffered in LDS with reg-staged
// prefetch; 1 barrier/caption via Sw dbuf. grid = (g=16, bt=16, nq=2).
// ---------------------------------------------------------------------------
__global__ __launch_bounds__(576, 3) void conv5_kernel(
    const float* __restrict__ img_embed, const unsigned short* __restrict__ Wp2F,
    const float* __restrict__ cap_repr, const float* __restrict__ cap_act,
    float* __restrict__ part_dot, float* __restrict__ part_ss)
{
    const int g = blockIdx.x, bt = blockIdx.y, nq = blockIdx.z;
    const int b0 = bt * 8;
    __shared__ int4 BsmV[3072];            // 48KB: A-staging, then B dbuf 2x24KB
    char* BsmRaw = (char*)BsmV;
    __shared__ float Sw[2][9][2][64];      // double-buffered partials
    const int tid = threadIdx.x;
    const int wv = tid >> 6, lane = tid & 63;
    const int lrow = lane & 31, khalf = lane >> 5;
    const int ioff = khalf * 16;

    // ---- stage A (8 images, swizzled, fused f32->bf16) ----
    const float* imgG = img_embed + (size_t)b0 * 36 * 1024 + g * 64;
    for (int idx = tid; idx < 2304; idx += 576) {
        const int row_img = idx >> 3, ch = idx & 7;
        const int bbs = row_img / 36;
        const int l = row_img - bbs * 36;
        const float* src = imgG + (size_t)row_img * 1024 + ch * 8;
        const float4 u = *reinterpret_cast<const float4*>(src);
        const float4 v = *reinterpret_cast<const float4*>(src + 4);
        unsigned short r8[8];
        r8[0]=f2bf(u.x); r8[1]=f2bf(u.y); r8[2]=f2bf(u.z); r8[3]=f2bf(u.w);
        r8[4]=f2bf(v.x); r8[5]=f2bf(v.y); r8[6]=f2bf(v.z); r8[7]=f2bf(v.w);
        const int arow = bbs * 38 + l + 1;
        const int byte = (arow * 128 + ch * 16) ^ ((arow & 7) << 4);
        *reinterpret_cast<int4*>(BsmRaw + byte) = *reinterpret_cast<const int4*>(r8);
    }
    if (tid < 128) {   // zero pad rows (pos 0 and 37 per image)
        const int rr = tid >> 3, ch = tid & 7;
        const int arow = (rr >> 1) * 38 + (rr & 1) * 37;
        const int byte = (arow * 128 + ch * 16) ^ ((arow & 7) << 4);
        int4 z; z.x = 0; z.y = 0; z.z = 0; z.w = 0;
        *reinterpret_cast<int4*>(BsmRaw + byte) = z;
    }
    __syncthreads();

    // ---- A-frags to registers: wave wv owns rows [32wv, 32wv+32) ----
    const int rg = wv * 32 + lrow;
    const int bbr = rg / 36;
    const int abase = bbr * 38 + (rg - bbr * 36);
    short8 afr[3][4];
    #pragma unroll
    for (int k = 0; k < 3; ++k)
        #pragma unroll
        for (int ks = 0; ks < 4; ++ks) {
            const int arow = abase + k;
            const int byte = (arow * 128 + ks * 32 + ioff) ^ ((arow & 7) << 4);
            afr[k][ks] = *reinterpret_cast<const short8*>(BsmRaw + byte);
        }
    const int rbase = wv * 32;
    const int bfirst = rbase / 36;
    const int bsplit = (bfirst + 1) * 36 - rbase;   // tile-rows >= bsplit -> img bfirst+1
    __syncthreads();   // all A reads done; BsmRaw becomes B double-buffer

    // ---- B prologue: stage caption n0 into buf0 ----
    const int n0 = nq * 16;
    int4 st0, st1, st2;
    {
        const unsigned short* WF = Wp2F + (size_t)(n0 * 16 + g) * 12288;
        st0 = *reinterpret_cast<const int4*>(WF + (size_t)tid * 8);
        st1 = *reinterpret_cast<const int4*>(WF + (size_t)(tid + 576) * 8);
        if (tid < 384) st2 = *reinterpret_cast<const int4*>(WF + (size_t)(tid + 1152) * 8);
        *reinterpret_cast<int4*>(BsmRaw + (size_t)tid * 16) = st0;
        *reinterpret_cast<int4*>(BsmRaw + (size_t)(tid + 576) * 16) = st1;
        if (tid < 384) *reinterpret_cast<int4*>(BsmRaw + (size_t)(tid + 1152) * 16) = st2;
    }
    __syncthreads();

    for (int ni = 0; ni < 16; ++ni) {
        const int n = n0 + ni;
        char* Bcur = BsmRaw + (size_t)(ni & 1) * 24576;
        char* Bnxt = BsmRaw + (size_t)((ni + 1) & 1) * 24576;

        if (ni < 15) {   // issue next caption's loads (latency hidden by MFMA)
            const unsigned short* WF = Wp2F + (size_t)((n + 1) * 16 + g) * 12288;
            st0 = *reinterpret_cast<const int4*>(WF + (size_t)tid * 8);
            st1 = *reinterpret_cast<const int4*>(WF + (size_t)(tid + 576) * 8);
            if (tid < 384) st2 = *reinterpret_cast<const int4*>(WF + (size_t)(tid + 1152) * 8);
        }

        f32x16 acc0 = {}, acc1 = {};
        #pragma unroll
        for (int k = 0; k < 3; ++k) {
            #pragma unroll
            for (int ks = 0; ks < 4; ++ks) {
                const char* fb = Bcur + k * 8192 + ks * 1024 + (size_t)lane * 16;
                const short8 bf0 = *reinterpret_cast<const short8*>(fb);
                const short8 bf1 = *reinterpret_cast<const short8*>(fb + 4096);
                acc0 = __builtin_amdgcn_mfma_f32_32x32x16_bf16(afr[k][ks], bf0, acc0, 0, 0, 0);
                acc1 = __builtin_amdgcn_mfma_f32_32x32x16_bf16(afr[k][ks], bf1, acc1, 0, 0, 0);
            }
        }

        if (ni < 15) {   // write staged B into inactive buffer
            *reinterpret_cast<int4*>(Bnxt + (size_t)tid * 16) = st0;
            *reinterpret_cast<int4*>(Bnxt + (size_t)(tid + 576) * 16) = st1;
            if (tid < 384) *reinterpret_cast<int4*>(Bnxt + (size_t)(tid + 1152) * 16) = st2;
        }

        // epilogue: leaky + per-image column sums -> Sw[ni&1]
        float s0A = 0.f, s0B = 0.f, s1A = 0.f, s1B = 0.f;
        #pragma unroll
        for (int reg = 0; reg < 16; ++reg) {
            const int rit = (reg & 3) + 8 * (reg >> 2) + 4 * khalf;
            const float v0 = leakyf(acc0[reg]);
            const float v1 = leakyf(acc1[reg]);
            if (rit >= bsplit) { s0B += v0; s1B += v1; }
            else               { s0A += v0; s1A += v1; }
        }
        s0A += __shfl_xor(s0A, 32); s0B += __shfl_xor(s0B, 32);
        s1A += __shfl_xor(s1A, 32); s1B += __shfl_xor(s1B, 32);
        const int q = ni & 1;
        if (khalf == 0) {
            Sw[q][wv][0][lrow]      = s0A;
            Sw[q][wv][0][32 + lrow] = s1A;
            if (bsplit < 32) {
                Sw[q][wv][1][lrow]      = s0B;
                Sw[q][wv][1][32 + lrow] = s1B;
            }
        }
        __syncthreads();   // Sw[q] complete; Bnxt staged

        if (tid < 128) {   // gather: img b = waves {b,slot1}+{b+1,slot0} (b>0)
            const int b = tid >> 4, j = tid & 15;
            const float4 ca4 = *reinterpret_cast<const float4*>(&cap_act [n * LATENT + g * CPG + j * 4]);
            const float4 cr4 = *reinterpret_cast<const float4*>(&cap_repr[n * LATENT + g * CPG + j * 4]);
            const float cav[4] = {ca4.x, ca4.y, ca4.z, ca4.w};
            const float crv[4] = {cr4.x, cr4.y, cr4.z, cr4.w};
            float d = 0.f, ss = 0.f;
            #pragma unroll
            for (int u = 0; u < 4; ++u) {
                const int o = j * 4 + u;
                const float S = (b == 0)
                    ? Sw[q][0][0][o] + Sw[q][1][0][o]
                    : Sw[q][b][1][o] + Sw[q][b + 1][0][o];
                const float tmp = S * cav[u];          // cap_act pre-scaled by 1/36
                d = fmaf(tmp, crv[u], d);
                ss = fmaf(tmp, tmp, ss);
            }
            #pragma unroll
            for (int off = 1; off <= 8; off <<= 1) {
                d += __shfl_xor(d, off);
                ss += __shfl_xor(ss, off);
            }
            if (j == 0) {
                part_dot[((size_t)n * BI + b0 + b) * NGROUPS + g] = d;
                part_ss [((size_t)n * BI + b0 + b) * NGROUPS + g] = ss;
            }
        }
    }
}

// ---------------------------------------------------------------------------
// Kernel 4: combine 16 group-partials -> sims[b*32+n]
// ---------------------------------------------------------------------------
__global__ __launch_bounds__(256) void final_kernel(
    const float* __restrict__ part_dot, const float* __restrict__ part_ss,
    const float* __restrict__ norm_capr, float* __restrict__ out)
{
    const int idx = blockIdx.x * 256 + threadIdx.x;   // 4096
    const int n = idx & 31;
    const int b = idx >> 5;
    const size_t base = ((size_t)n * BI + b) * NGROUPS;
    float d = 0.f, s = 0.f;
    #pragma unroll
    for (int g = 0; g < NGROUPS; ++g) { d += part_dot[base + g]; s += part_ss[base + g]; }
    out[b * BC + n] = d / (sqrtf(s) * norm_capr[n]);
}

// ---------------------------------------------------------------------------
extern "C" void kernel_launch(void* const* d_in, const int* in_sizes, int n_in,
                              void* d_out, int out_size, void* d_ws, size_t ws_size,
                              hipStream_t stream) {
    const float* img_embed = (const float*)d_in[0];   // (128, 36, 1024)
    const float* cap_embed = (const float*)d_in[1];   // (32, 50, 1024)
    const int*   lens      = (const int*)  d_in[2];   // (32,)
    const float* red_w     = (const float*)d_in[3];   // (1024, 256)
    const float* red_b     = (const float*)d_in[4];   // (256,)
    const float* proj_w    = (const float*)d_in[5];   // (256, 196608)
    const float* proj_b    = (const float*)d_in[6];   // (196608,)
    float* out = (float*)d_out;                        // (128, 32)

    char* ws = (char*)d_ws;
    unsigned short* Wp2F   = (unsigned short*)(ws);                    // 12,582,912 B
    float* cap_repr  = (float*)(ws + 22020096);                        //    131,072 B
    float* cap_act   = (float*)(ws + 22151168);                        //    131,072 B
    unsigned short* qbfF = (unsigned short*)(ws + 22282240);           //     16,384 B
    float* norm_capr = (float*)(ws + 22315008);                        //        512 B
    float* part_dot  = (float*)(ws + 22315520);                        //    262,144 B
    float* part_ss   = (float*)(ws + 22577664);                        //    262,144 B

    hipLaunchKernelGGL(cap_mean_kernel, dim3(BC), dim3(256), 0, stream,
                       cap_embed, lens, cap_repr, cap_act, norm_capr);
    hipLaunchKernelGGL(q_kernel, dim3(8, BC), dim3(256), 0, stream,
                       cap_repr, red_w, red_b, qbfF);
    hipLaunchKernelGGL(wgen8_kernel, dim3(1024), dim3(384), 0, stream,
                       qbfF, proj_w, proj_b, Wp2F);
    hipLaunchKernelGGL(conv5_kernel, dim3(NGROUPS, 16, 2), dim3(576), 0, stream,
                       img_embed, Wp2F, cap_repr, cap_act, part_dot, part_ss);
    hipLaunchKernelGGL(final_kernel, dim3(16), dim3(256), 0, stream,
                       part_dot, part_ss, norm_capr, out);
}

// Round 9
// 180.848 us; speedup vs baseline: 1.2403x; 1.0315x over previous
//
#include <hip/hip_runtime.h>
#include <math.h>

#define LATENT 1024
#define QDIM 256
#define NW 196608           // LATENT * CPG * K
#define BI 128
#define BC 32
#define TT 50
#define REGIONS 36
#define NGROUPS 16
#define CPG 64
#define NEG 0.1f

typedef __attribute__((ext_vector_type(8))) short short8;
typedef __attribute__((ext_vector_type(16))) float f32x16;

__device__ __forceinline__ float leakyf(float x){ return x > 0.f ? x : NEG * x; }

__device__ __forceinline__ unsigned short f2bf(float x){
    union { float f; unsigned int u; } v; v.f = x;
    unsigned int r = v.u + 0x7FFFu + ((v.u >> 16) & 1u);   // RNE
    return (unsigned short)(r >> 16);
}

// ---------------------------------------------------------------------------
// Kernel 1a: masked mean + gate(pre-scaled by 1/36) + ||cap_repr||.
// ---------------------------------------------------------------------------
__global__ __launch_bounds__(256) void cap_mean_kernel(
    const float* __restrict__ cap_embed, const int* __restrict__ lens,
    float* __restrict__ cap_repr, float* __restrict__ cap_act,
    float* __restrict__ norm_capr)
{
    const int n = blockIdx.x;
    const int len = lens[n];
    const float invl = 1.f / (float)len;
    const int c4 = threadIdx.x;
    const float* base = cap_embed + (size_t)n * TT * LATENT + c4 * 4;
    float4 s = {0.f, 0.f, 0.f, 0.f};
    for (int t = 0; t < len; ++t) {
        const float4 v = *reinterpret_cast<const float4*>(base + (size_t)t * LATENT);
        s.x += v.x; s.y += v.y; s.z += v.z; s.w += v.w;
    }
    float4 m = {s.x * invl, s.y * invl, s.z * invl, s.w * invl};
    *reinterpret_cast<float4*>(cap_repr + n * LATENT + c4 * 4) = m;
    const float sc = 1.f / 36.f;
    float4 a = {leakyf(m.x) * sc, leakyf(m.y) * sc, leakyf(m.z) * sc, leakyf(m.w) * sc};
    *reinterpret_cast<float4*>(cap_act + n * LATENT + c4 * 4) = a;
    float ss = m.x*m.x + m.y*m.y + m.z*m.z + m.w*m.w;
    #pragma unroll
    for (int off = 32; off; off >>= 1) ss += __shfl_xor(ss, off);
    __shared__ float red4[4];
    if ((threadIdx.x & 63) == 0) red4[threadIdx.x >> 6] = ss;
    __syncthreads();
    if (threadIdx.x == 0) norm_capr[n] = sqrtf(red4[0] + red4[1] + red4[2] + red4[3]);
}

// ---------------------------------------------------------------------------
// Kernel 1b: q = cap_repr @ red_w + red_b, packed into bf16 frag layout
// qbfF: elem (r>>4)*512 + ((r>>3)&1)*256 + n*8 + (r&7)  (16KB total)
// ---------------------------------------------------------------------------
__global__ __launch_bounds__(256) void q_kernel(
    const float* __restrict__ cap_repr, const float* __restrict__ red_w,
    const float* __restrict__ red_b, unsigned short* __restrict__ qbfF)
{
    const int cg = blockIdx.x, n = blockIdx.y;
    const int col = threadIdx.x & 31, ks = threadIdx.x >> 5;
    const float* cr = cap_repr + n * LATENT;
    float p = 0.f;
    const int r0 = ks * 128;
    for (int r = r0; r < r0 + 128; ++r)
        p = fmaf(cr[r], red_w[(size_t)r * QDIM + cg * 32 + col], p);
    __shared__ float part[256];
    part[threadIdx.x] = p;
    __syncthreads();
    if (threadIdx.x < 32) {
        float s = red_b[cg * 32 + col];
        #pragma unroll
        for (int k = 0; k < 8; ++k) s += part[k * 32 + col];
        const int r = cg * 32 + col;
        const int elem = (r >> 4) * 512 + ((r >> 3) & 1) * 256 + n * 8 + (r & 7);
        qbfF[elem] = f2bf(s);
    }
}

// ---------------------------------------------------------------------------
// Kernel 2: wgen9 — barrier-free MFMA W-GEMM. Block = one (g,o) slice
// (192 cols), 384 thr = 6 waves; wave wv owns cols [32wv,32wv+32).
// A = proj_w fragments loaded DIRECTLY from global (lane = col, 8 stride-NW
// dwords/step, f32->bf16 in register); B = q frags held in registers.
// No LDS, no barriers in the K-loop -> full TLP latency hiding.
// D[row=col_w][col=n]. Epilogue: bias + softmax(K=3) + frag-major pack.
// ---------------------------------------------------------------------------
__global__ __launch_bounds__(384) void wgen9_kernel(
    const unsigned short* __restrict__ qbfF, const float* __restrict__ proj_w,
    const float* __restrict__ proj_b, unsigned short* __restrict__ Wp2F)
{
    __shared__ float L[192 * 33];      // logits [col][n]
    __shared__ float pbs[192];
    const int tid = threadIdx.x;
    const int g = blockIdx.x >> 6, o = blockIdx.x & 63;
    const int colbase = (g * 64 + o) * 192;
    const int wv = tid >> 6, lane = tid & 63;
    const int lrow = lane & 31, khalf = lane >> 5;

    if (tid < 192) pbs[tid] = proj_b[colbase + tid];

    // B-frags: q in registers (16 x b128, coalesced)
    short8 qfr[16];
    {
        const unsigned short* qp = qbfF + (size_t)lane * 8;
        #pragma unroll
        for (int s = 0; s < 16; ++s)
            qfr[s] = *reinterpret_cast<const short8*>(qp + s * 512);
    }

    // per-lane A base: col = colbase + wv*32 + lrow, r-offset khalf*8
    const float* pw0 = proj_w + (size_t)(khalf * 8) * NW + colbase + wv * 32 + lrow;

    float a[8], b[8];
    #pragma unroll
    for (int j = 0; j < 8; ++j) a[j] = pw0[(size_t)j * NW];

    f32x16 acc = {};
    #pragma unroll
    for (int s = 0; s < 16; ++s) {
        if (s < 15) {                      // prefetch next step's 8 rows
            const float* pwn = pw0 + (size_t)((s + 1) * 16) * NW;
            #pragma unroll
            for (int j = 0; j < 8; ++j) b[j] = pwn[(size_t)j * NW];
        }
        unsigned short u[8];
        #pragma unroll
        for (int j = 0; j < 8; ++j) u[j] = f2bf(a[j]);
        const short8 af = *reinterpret_cast<const short8*>(u);
        acc = __builtin_amdgcn_mfma_f32_32x32x16_bf16(af, qfr[s], acc, 0, 0, 0);
        #pragma unroll
        for (int j = 0; j < 8; ++j) a[j] = b[j];
    }

    __syncthreads();                        // pbs visible; L about to be written
    // C: row(col_w) = (reg&3)+8*(reg>>2)+4*khalf, col(n) = lane&31
    #pragma unroll
    for (int reg = 0; reg < 16; ++reg) {
        const int rit = (reg & 3) + 8 * (reg >> 2) + 4 * khalf;
        const int c = wv * 32 + rit;
        L[c * 33 + lrow] = acc[reg] + pbs[c];
    }
    __syncthreads();

    // softmax over k-triples + frag-major bf16 pack
    const int nt = o >> 5, lrow_o = o & 31;
    for (int idx = tid; idx < 2048; idx += 384) {
        const int n = idx & 31, i = idx >> 5;     // i < 64
        const int c = i * 3;
        const float x0 = L[c * 33 + n], x1 = L[(c+1)*33 + n], x2 = L[(c+2)*33 + n];
        const float m = fmaxf(fmaxf(x0, x1), x2);
        const float e0 = expf(x0 - m), e1 = expf(x1 - m), e2 = expf(x2 - m);
        const float inv = 1.f / (e0 + e1 + e2);
        const int ks = i >> 4, kh = (i >> 3) & 1, j = i & 7;
        const size_t base = (size_t)(n * 16 + g) * 12288
                          + (size_t)(nt * 4 + ks) * 512
                          + kh * 256 + lrow_o * 8 + j;
        Wp2F[base]        = f2bf(e0 * inv);   // k=0
        Wp2F[base + 4096] = f2bf(e1 * inv);   // k=1 (+8 frags)
        Wp2F[base + 8192] = f2bf(e2 * inv);   // k=2
    }
}

// ---------------------------------------------------------------------------
// Kernel 3: conv5 — 576 thr = 9 thin waves, 1 M-tile (32 rows) per wave.
// A-frags cached in registers; B double-buffered in LDS with reg-staged
// prefetch; 1 barrier/caption via Sw dbuf. grid = (g=16, bt=16, nq=2).
// ---------------------------------------------------------------------------
__global__ __launch_bounds__(576, 3) void conv5_kernel(
    const float* __restrict__ img_embed, const unsigned short* __restrict__ Wp2F,
    const float* __restrict__ cap_repr, const float* __restrict__ cap_act,
    float* __restrict__ part_dot, float* __restrict__ part_ss)
{
    const int g = blockIdx.x, bt = blockIdx.y, nq = blockIdx.z;
    const int b0 = bt * 8;
    __shared__ int4 BsmV[3072];            // 48KB: A-staging, then B dbuf 2x24KB
    char* BsmRaw = (char*)BsmV;
    __shared__ float Sw[2][9][2][64];      // double-buffered partials
    const int tid = threadIdx.x;
    const int wv = tid >> 6, lane = tid & 63;
    const int lrow = lane & 31, khalf = lane >> 5;
    const int ioff = khalf * 16;

    // ---- stage A (8 images, swizzled, fused f32->bf16) ----
    const float* imgG = img_embed + (size_t)b0 * 36 * 1024 + g * 64;
    for (int idx = tid; idx < 2304; idx += 576) {
        const int row_img = idx >> 3, ch = idx & 7;
        const int bbs = row_img / 36;
        const int l = row_img - bbs * 36;
        const float* src = imgG + (size_t)row_img * 1024 + ch * 8;
        const float4 u = *reinterpret_cast<const float4*>(src);
        const float4 v = *reinterpret_cast<const float4*>(src + 4);
        unsigned short r8[8];
        r8[0]=f2bf(u.x); r8[1]=f2bf(u.y); r8[2]=f2bf(u.z); r8[3]=f2bf(u.w);
        r8[4]=f2bf(v.x); r8[5]=f2bf(v.y); r8[6]=f2bf(v.z); r8[7]=f2bf(v.w);
        const int arow = bbs * 38 + l + 1;
        const int byte = (arow * 128 + ch * 16) ^ ((arow & 7) << 4);
        *reinterpret_cast<int4*>(BsmRaw + byte) = *reinterpret_cast<const int4*>(r8);
    }
    if (tid < 128) {   // zero pad rows (pos 0 and 37 per image)
        const int rr = tid >> 3, ch = tid & 7;
        const int arow = (rr >> 1) * 38 + (rr & 1) * 37;
        const int byte = (arow * 128 + ch * 16) ^ ((arow & 7) << 4);
        int4 z; z.x = 0; z.y = 0; z.z = 0; z.w = 0;
        *reinterpret_cast<int4*>(BsmRaw + byte) = z;
    }
    __syncthreads();

    // ---- A-frags to registers: wave wv owns rows [32wv, 32wv+32) ----
    const int rg = wv * 32 + lrow;
    const int bbr = rg / 36;
    const int abase = bbr * 38 + (rg - bbr * 36);
    short8 afr[3][4];
    #pragma unroll
    for (int k = 0; k < 3; ++k)
        #pragma unroll
        for (int ks = 0; ks < 4; ++ks) {
            const int arow = abase + k;
            const int byte = (arow * 128 + ks * 32 + ioff) ^ ((arow & 7) << 4);
            afr[k][ks] = *reinterpret_cast<const short8*>(BsmRaw + byte);
        }
    const int rbase = wv * 32;
    const int bfirst = rbase / 36;
    const int bsplit = (bfirst + 1) * 36 - rbase;   // tile-rows >= bsplit -> img bfirst+1
    __syncthreads();   // all A reads done; BsmRaw becomes B double-buffer

    // ---- B prologue: stage caption n0 into buf0 ----
    const int n0 = nq * 16;
    int4 st0, st1, st2;
    {
        const unsigned short* WF = Wp2F + (size_t)(n0 * 16 + g) * 12288;
        st0 = *reinterpret_cast<const int4*>(WF + (size_t)tid * 8);
        st1 = *reinterpret_cast<const int4*>(WF + (size_t)(tid + 576) * 8);
        if (tid < 384) st2 = *reinterpret_cast<const int4*>(WF + (size_t)(tid + 1152) * 8);
        *reinterpret_cast<int4*>(BsmRaw + (size_t)tid * 16) = st0;
        *reinterpret_cast<int4*>(BsmRaw + (size_t)(tid + 576) * 16) = st1;
        if (tid < 384) *reinterpret_cast<int4*>(BsmRaw + (size_t)(tid + 1152) * 16) = st2;
    }
    __syncthreads();

    for (int ni = 0; ni < 16; ++ni) {
        const int n = n0 + ni;
        char* Bcur = BsmRaw + (size_t)(ni & 1) * 24576;
        char* Bnxt = BsmRaw + (size_t)((ni + 1) & 1) * 24576;

        if (ni < 15) {   // issue next caption's loads (latency hidden by MFMA)
            const unsigned short* WF = Wp2F + (size_t)((n + 1) * 16 + g) * 12288;
            st0 = *reinterpret_cast<const int4*>(WF + (size_t)tid * 8);
            st1 = *reinterpret_cast<const int4*>(WF + (size_t)(tid + 576) * 8);
            if (tid < 384) st2 = *reinterpret_cast<const int4*>(WF + (size_t)(tid + 1152) * 8);
        }

        f32x16 acc0 = {}, acc1 = {};
        #pragma unroll
        for (int k = 0; k < 3; ++k) {
            #pragma unroll
            for (int ks = 0; ks < 4; ++ks) {
                const char* fb = Bcur + k * 8192 + ks * 1024 + (size_t)lane * 16;
                const short8 bf0 = *reinterpret_cast<const short8*>(fb);
                const short8 bf1 = *reinterpret_cast<const short8*>(fb + 4096);
                acc0 = __builtin_amdgcn_mfma_f32_32x32x16_bf16(afr[k][ks], bf0, acc0, 0, 0, 0);
                acc1 = __builtin_amdgcn_mfma_f32_32x32x16_bf16(afr[k][ks], bf1, acc1, 0, 0, 0);
            }
        }

        if (ni < 15) {   // write staged B into inactive buffer
            *reinterpret_cast<int4*>(Bnxt + (size_t)tid * 16) = st0;
            *reinterpret_cast<int4*>(Bnxt + (size_t)(tid + 576) * 16) = st1;
            if (tid < 384) *reinterpret_cast<int4*>(Bnxt + (size_t)(tid + 1152) * 16) = st2;
        }

        // epilogue: leaky + per-image column sums -> Sw[ni&1]
        float s0A = 0.f, s0B = 0.f, s1A = 0.f, s1B = 0.f;
        #pragma unroll
        for (int reg = 0; reg < 16; ++reg) {
            const int rit = (reg & 3) + 8 * (reg >> 2) + 4 * khalf;
            const float v0 = leakyf(acc0[reg]);
            const float v1 = leakyf(acc1[reg]);
            if (rit >= bsplit) { s0B += v0; s1B += v1; }
            else               { s0A += v0; s1A += v1; }
        }
        s0A += __shfl_xor(s0A, 32); s0B += __shfl_xor(s0B, 32);
        s1A += __shfl_xor(s1A, 32); s1B += __shfl_xor(s1B, 32);
        const int q = ni & 1;
        if (khalf == 0) {
            Sw[q][wv][0][lrow]      = s0A;
            Sw[q][wv][0][32 + lrow] = s1A;
            if (bsplit < 32) {
                Sw[q][wv][1][lrow]      = s0B;
                Sw[q][wv][1][32 + lrow] = s1B;
            }
        }
        __syncthreads();   // Sw[q] complete; Bnxt staged

        if (tid < 128) {   // gather: img b = waves {b,slot1}+{b+1,slot0} (b>0)
            const int b = tid >> 4, j = tid & 15;
            const float4 ca4 = *reinterpret_cast<const float4*>(&cap_act [n * LATENT + g * CPG + j * 4]);
            const float4 cr4 = *reinterpret_cast<const float4*>(&cap_repr[n * LATENT + g * CPG + j * 4]);
            const float cav[4] = {ca4.x, ca4.y, ca4.z, ca4.w};
            const float crv[4] = {cr4.x, cr4.y, cr4.z, cr4.w};
            float d = 0.f, ss = 0.f;
            #pragma unroll
            for (int u = 0; u < 4; ++u) {
                const int o = j * 4 + u;
                const float S = (b == 0)
                    ? Sw[q][0][0][o] + Sw[q][1][0][o]
                    : Sw[q][b][1][o] + Sw[q][b + 1][0][o];
                const float tmp = S * cav[u];          // cap_act pre-scaled by 1/36
                d = fmaf(tmp, crv[u], d);
                ss = fmaf(tmp, tmp, ss);
            }
            #pragma unroll
            for (int off = 1; off <= 8; off <<= 1) {
                d += __shfl_xor(d, off);
                ss += __shfl_xor(ss, off);
            }
            if (j == 0) {
                part_dot[((size_t)n * BI + b0 + b) * NGROUPS + g] = d;
                part_ss [((size_t)n * BI + b0 + b) * NGROUPS + g] = ss;
            }
        }
    }
}

// ---------------------------------------------------------------------------
// Kernel 4: combine 16 group-partials -> sims[b*32+n]
// ---------------------------------------------------------------------------
__global__ __launch_bounds__(256) void final_kernel(
    const float* __restrict__ part_dot, const float* __restrict__ part_ss,
    const float* __restrict__ norm_capr, float* __restrict__ out)
{
    const int idx = blockIdx.x * 256 + threadIdx.x;   // 4096
    const int n = idx & 31;
    const int b = idx >> 5;
    const size_t base = ((size_t)n * BI + b) * NGROUPS;
    float d = 0.f, s = 0.f;
    #pragma unroll
    for (int g = 0; g < NGROUPS; ++g) { d += part_dot[base + g]; s += part_ss[base + g]; }
    out[b * BC + n] = d / (sqrtf(s) * norm_capr[n]);
}

// ---------------------------------------------------------------------------
extern "C" void kernel_launch(void* const* d_in, const int* in_sizes, int n_in,
                              void* d_out, int out_size, void* d_ws, size_t ws_size,
                              hipStream_t stream) {
    const float* img_embed = (const float*)d_in[0];   // (128, 36, 1024)
    const float* cap_embed = (const float*)d_in[1];   // (32, 50, 1024)
    const int*   lens      = (const int*)  d_in[2];   // (32,)
    const float* red_w     = (const float*)d_in[3];   // (1024, 256)
    const float* red_b     = (const float*)d_in[4];   // (256,)
    const float* proj_w    = (const float*)d_in[5];   // (256, 196608)
    const float* proj_b    = (const float*)d_in[6];   // (196608,)
    float* out = (float*)d_out;                        // (128, 32)

    char* ws = (char*)d_ws;
    unsigned short* Wp2F   = (unsigned short*)(ws);                    // 12,582,912 B
    float* cap_repr  = (float*)(ws + 22020096);                        //    131,072 B
    float* cap_act   = (float*)(ws + 22151168);                        //    131,072 B
    unsigned short* qbfF = (unsigned short*)(ws + 22282240);           //     16,384 B
    float* norm_capr = (float*)(ws + 22315008);                        //        512 B
    float* part_dot  = (float*)(ws + 22315520);                        //    262,144 B
    float* part_ss   = (float*)(ws + 22577664);                        //    262,144 B

    hipLaunchKernelGGL(cap_mean_kernel, dim3(BC), dim3(256), 0, stream,
                       cap_embed, lens, cap_repr, cap_act, norm_capr);
    hipLaunchKernelGGL(q_kernel, dim3(8, BC), dim3(256), 0, stream,
                       cap_repr, red_w, red_b, qbfF);
    hipLaunchKernelGGL(wgen9_kernel, dim3(1024), dim3(384), 0, stream,
                       qbfF, proj_w, proj_b, Wp2F);
    hipLaunchKernelGGL(conv5_kernel, dim3(NGROUPS, 16, 2), dim3(576), 0, stream,
                       img_embed, Wp2F, cap_repr, cap_act, part_dot, part_ss);
    hipLaunchKernelGGL(final_kernel, dim3(16), dim3(256), 0, stream,
                       part_dot, part_ss, norm_capr, out);
}

// Round 10
// 176.644 us; speedup vs baseline: 1.2698x; 1.0238x over previous
//
#include <hip/hip_runtime.h>
#include <math.h>

#define LATENT 1024
#define QDIM 256
#define NW 196608           // LATENT * CPG * K
#define BI 128
#define BC 32
#define TT 50
#define REGIONS 36
#define NGROUPS 16
#define CPG 64
#define NEG 0.1f

typedef __attribute__((ext_vector_type(8))) short short8;
typedef __attribute__((ext_vector_type(16))) float f32x16;

__device__ __forceinline__ float leakyf(float x){ return x > 0.f ? x : NEG * x; }

__device__ __forceinline__ unsigned short f2bf(float x){
    union { float f; unsigned int u; } v; v.f = x;
    unsigned int r = v.u + 0x7FFFu + ((v.u >> 16) & 1u);   // RNE
    return (unsigned short)(r >> 16);
}

// ---------------------------------------------------------------------------
// Kernel 1a: masked mean + gate(pre-scaled by 1/36) + ||cap_repr||.
// ---------------------------------------------------------------------------
__global__ __launch_bounds__(256) void cap_mean_kernel(
    const float* __restrict__ cap_embed, const int* __restrict__ lens,
    float* __restrict__ cap_repr, float* __restrict__ cap_act,
    float* __restrict__ norm_capr)
{
    const int n = blockIdx.x;
    const int len = lens[n];
    const float invl = 1.f / (float)len;
    const int c4 = threadIdx.x;
    const float* base = cap_embed + (size_t)n * TT * LATENT + c4 * 4;
    float4 s = {0.f, 0.f, 0.f, 0.f};
    for (int t = 0; t < len; ++t) {
        const float4 v = *reinterpret_cast<const float4*>(base + (size_t)t * LATENT);
        s.x += v.x; s.y += v.y; s.z += v.z; s.w += v.w;
    }
    float4 m = {s.x * invl, s.y * invl, s.z * invl, s.w * invl};
    *reinterpret_cast<float4*>(cap_repr + n * LATENT + c4 * 4) = m;
    const float sc = 1.f / 36.f;
    float4 a = {leakyf(m.x) * sc, leakyf(m.y) * sc, leakyf(m.z) * sc, leakyf(m.w) * sc};
    *reinterpret_cast<float4*>(cap_act + n * LATENT + c4 * 4) = a;
    float ss = m.x*m.x + m.y*m.y + m.z*m.z + m.w*m.w;
    #pragma unroll
    for (int off = 32; off; off >>= 1) ss += __shfl_xor(ss, off);
    __shared__ float red4[4];
    if ((threadIdx.x & 63) == 0) red4[threadIdx.x >> 6] = ss;
    __syncthreads();
    if (threadIdx.x == 0) norm_capr[n] = sqrtf(red4[0] + red4[1] + red4[2] + red4[3]);
}

// ---------------------------------------------------------------------------
// Kernel 1b: q = cap_repr @ red_w + red_b, packed into bf16 frag layout
// qbfF: elem (r>>4)*512 + ((r>>3)&1)*256 + n*8 + (r&7)  (16KB total)
// ---------------------------------------------------------------------------
__global__ __launch_bounds__(256) void q_kernel(
    const float* __restrict__ cap_repr, const float* __restrict__ red_w,
    const float* __restrict__ red_b, unsigned short* __restrict__ qbfF)
{
    const int cg = blockIdx.x, n = blockIdx.y;
    const int col = threadIdx.x & 31, ks = threadIdx.x >> 5;
    const float* cr = cap_repr + n * LATENT;
    float p = 0.f;
    const int r0 = ks * 128;
    for (int r = r0; r < r0 + 128; ++r)
        p = fmaf(cr[r], red_w[(size_t)r * QDIM + cg * 32 + col], p);
    __shared__ float part[256];
    part[threadIdx.x] = p;
    __syncthreads();
    if (threadIdx.x < 32) {
        float s = red_b[cg * 32 + col];
        #pragma unroll
        for (int k = 0; k < 8; ++k) s += part[k * 32 + col];
        const int r = cg * 32 + col;
        const int elem = (r >> 4) * 512 + ((r >> 3) & 1) * 256 + n * 8 + (r & 7);
        qbfF[elem] = f2bf(s);
    }
}

// ---------------------------------------------------------------------------
// Kernel 2: wgen10 — wide-panel MFMA W-GEMM. Block = 768 cols (4 o-slices),
// grid = 256 (exactly 1 block/CU, all co-resident -> lockstep streaming).
// 512 thr = 8 waves; wave owns 3 adjacent 32-col M-tiles -> 3KB contiguous
// per row per block (vs 768B before: fewer DRAM activates per byte).
// A = proj_w direct from global (f32->bf16 in reg); B = q frags in reg.
// Logits -> 96KB f32 LDS; softmax(K=3) + frag-major pack epilogue.
// ---------------------------------------------------------------------------
__global__ __launch_bounds__(512, 2) void wgen10_kernel(
    const unsigned short* __restrict__ qbfF, const float* __restrict__ proj_w,
    const float* __restrict__ proj_b, unsigned short* __restrict__ Wp2F)
{
    __shared__ float L[768 * 32];      // 96KB logits [col][n]
    __shared__ float pbs[768];
    const int tid = threadIdx.x;
    const int bx = blockIdx.x;
    const int colbase = bx * 768;
    const int wv = tid >> 6, lane = tid & 63;
    const int lrow = lane & 31, khalf = lane >> 5;

    for (int i = tid; i < 768; i += 512) pbs[i] = proj_b[colbase + i];

    // B-frags: q in registers (16 x b128, coalesced)
    short8 qfr[16];
    {
        const unsigned short* qp = qbfF + (size_t)lane * 8;
        #pragma unroll
        for (int s = 0; s < 16; ++s)
            qfr[s] = *reinterpret_cast<const short8*>(qp + s * 512);
    }

    // per-lane A bases: 3 adjacent 32-col tiles, r-offset khalf*8
    const float* pw0 = proj_w + (size_t)(khalf * 8) * NW + colbase + wv * 96 + lrow;
    const float* pw1 = pw0 + 32;
    const float* pw2 = pw0 + 64;

    float a0[8], a1[8], a2[8], b0[8], b1[8], b2[8];
    #pragma unroll
    for (int j = 0; j < 8; ++j) {
        a0[j] = pw0[(size_t)j * NW];
        a1[j] = pw1[(size_t)j * NW];
        a2[j] = pw2[(size_t)j * NW];
    }

    f32x16 acc0 = {}, acc1 = {}, acc2 = {};
    #pragma unroll
    for (int s = 0; s < 16; ++s) {
        if (s < 15) {                      // prefetch next step's rows
            const size_t roff = (size_t)((s + 1) * 16) * NW;
            #pragma unroll
            for (int j = 0; j < 8; ++j) {
                b0[j] = pw0[roff + (size_t)j * NW];
                b1[j] = pw1[roff + (size_t)j * NW];
                b2[j] = pw2[roff + (size_t)j * NW];
            }
        }
        unsigned short u0[8], u1[8], u2[8];
        #pragma unroll
        for (int j = 0; j < 8; ++j) {
            u0[j] = f2bf(a0[j]); u1[j] = f2bf(a1[j]); u2[j] = f2bf(a2[j]);
        }
        acc0 = __builtin_amdgcn_mfma_f32_32x32x16_bf16(*reinterpret_cast<const short8*>(u0), qfr[s], acc0, 0, 0, 0);
        acc1 = __builtin_amdgcn_mfma_f32_32x32x16_bf16(*reinterpret_cast<const short8*>(u1), qfr[s], acc1, 0, 0, 0);
        acc2 = __builtin_amdgcn_mfma_f32_32x32x16_bf16(*reinterpret_cast<const short8*>(u2), qfr[s], acc2, 0, 0, 0);
        #pragma unroll
        for (int j = 0; j < 8; ++j) { a0[j] = b0[j]; a1[j] = b1[j]; a2[j] = b2[j]; }
    }

    __syncthreads();   // pbs staged by all threads; now safe to read
    // C: row(col_w) = (reg&3)+8*(reg>>2)+4*khalf, col(n) = lane&31
    #pragma unroll
    for (int reg = 0; reg < 16; ++reg) {
        const int rit = (reg & 3) + 8 * (reg >> 2) + 4 * khalf;
        const int c = wv * 96 + rit;
        L[c * 32 + lrow]        = acc0[reg] + pbs[c];
        L[(c + 32) * 32 + lrow] = acc1[reg] + pbs[c + 32];
        L[(c + 64) * 32 + lrow] = acc2[reg] + pbs[c + 64];
    }
    __syncthreads();

    // softmax over k-triples + frag-major bf16 pack (256 triples x 32 n)
    const int g = bx >> 4;
    const int obase = (bx & 15) * 4;
    for (int idx = tid; idx < 8192; idx += 512) {
        const int n = idx & 31, i = idx >> 5;     // i < 256 triples
        const int c = i * 3;
        const float x0 = L[c * 32 + n], x1 = L[(c+1)*32 + n], x2 = L[(c+2)*32 + n];
        const float m = fmaxf(fmaxf(x0, x1), x2);
        const float e0 = expf(x0 - m), e1 = expf(x1 - m), e2 = expf(x2 - m);
        const float inv = 1.f / (e0 + e1 + e2);
        const int o = obase + (i >> 6);
        const int ii = i & 63;
        const int nt = o >> 5, lrow_o = o & 31;
        const int ks = ii >> 4, kh = (ii >> 3) & 1, j = ii & 7;
        const size_t base = (size_t)(n * 16 + g) * 12288
                          + (size_t)(nt * 4 + ks) * 512
                          + kh * 256 + lrow_o * 8 + j;
        Wp2F[base]        = f2bf(e0 * inv);   // k=0
        Wp2F[base + 4096] = f2bf(e1 * inv);   // k=1 (+8 frags)
        Wp2F[base + 8192] = f2bf(e2 * inv);   // k=2
    }
}

// ---------------------------------------------------------------------------
// Kernel 3: conv5 — 576 thr = 9 thin waves, 1 M-tile (32 rows) per wave.
// A-frags cached in registers; B double-buffered in LDS with reg-staged
// prefetch; 1 barrier/caption via Sw dbuf. grid = (g=16, bt=16, nq=2).
// ---------------------------------------------------------------------------
__global__ __launch_bounds__(576, 3) void conv5_kernel(
    const float* __restrict__ img_embed, const unsigned short* __restrict__ Wp2F,
    const float* __restrict__ cap_repr, const float* __restrict__ cap_act,
    float* __restrict__ part_dot, float* __restrict__ part_ss)
{
    const int g = blockIdx.x, bt = blockIdx.y, nq = blockIdx.z;
    const int b0 = bt * 8;
    __shared__ int4 BsmV[3072];            // 48KB: A-staging, then B dbuf 2x24KB
    char* BsmRaw = (char*)BsmV;
    __shared__ float Sw[2][9][2][64];      // double-buffered partials
    const int tid = threadIdx.x;
    const int wv = tid >> 6, lane = tid & 63;
    const int lrow = lane & 31, khalf = lane >> 5;
    const int ioff = khalf * 16;

    // ---- stage A (8 images, swizzled, fused f32->bf16) ----
    const float* imgG = img_embed + (size_t)b0 * 36 * 1024 + g * 64;
    for (int idx = tid; idx < 2304; idx += 576) {
        const int row_img = idx >> 3, ch = idx & 7;
        const int bbs = row_img / 36;
        const int l = row_img - bbs * 36;
        const float* src = imgG + (size_t)row_img * 1024 + ch * 8;
        const float4 u = *reinterpret_cast<const float4*>(src);
        const float4 v = *reinterpret_cast<const float4*>(src + 4);
        unsigned short r8[8];
        r8[0]=f2bf(u.x); r8[1]=f2bf(u.y); r8[2]=f2bf(u.z); r8[3]=f2bf(u.w);
        r8[4]=f2bf(v.x); r8[5]=f2bf(v.y); r8[6]=f2bf(v.z); r8[7]=f2bf(v.w);
        const int arow = bbs * 38 + l + 1;
        const int byte = (arow * 128 + ch * 16) ^ ((arow & 7) << 4);
        *reinterpret_cast<int4*>(BsmRaw + byte) = *reinterpret_cast<const int4*>(r8);
    }
    if (tid < 128) {   // zero pad rows (pos 0 and 37 per image)
        const int rr = tid >> 3, ch = tid & 7;
        const int arow = (rr >> 1) * 38 + (rr & 1) * 37;
        const int byte = (arow * 128 + ch * 16) ^ ((arow & 7) << 4);
        int4 z; z.x = 0; z.y = 0; z.z = 0; z.w = 0;
        *reinterpret_cast<int4*>(BsmRaw + byte) = z;
    }
    __syncthreads();

    // ---- A-frags to registers: wave wv owns rows [32wv, 32wv+32) ----
    const int rg = wv * 32 + lrow;
    const int bbr = rg / 36;
    const int abase = bbr * 38 + (rg - bbr * 36);
    short8 afr[3][4];
    #pragma unroll
    for (int k = 0; k < 3; ++k)
        #pragma unroll
        for (int ks = 0; ks < 4; ++ks) {
            const int arow = abase + k;
            const int byte = (arow * 128 + ks * 32 + ioff) ^ ((arow & 7) << 4);
            afr[k][ks] = *reinterpret_cast<const short8*>(BsmRaw + byte);
        }
    const int rbase = wv * 32;
    const int bfirst = rbase / 36;
    const int bsplit = (bfirst + 1) * 36 - rbase;   // tile-rows >= bsplit -> img bfirst+1
    __syncthreads();   // all A reads done; BsmRaw becomes B double-buffer

    // ---- B prologue: stage caption n0 into buf0 ----
    const int n0 = nq * 16;
    int4 st0, st1, st2;
    {
        const unsigned short* WF = Wp2F + (size_t)(n0 * 16 + g) * 12288;
        st0 = *reinterpret_cast<const int4*>(WF + (size_t)tid * 8);
        st1 = *reinterpret_cast<const int4*>(WF + (size_t)(tid + 576) * 8);
        if (tid < 384) st2 = *reinterpret_cast<const int4*>(WF + (size_t)(tid + 1152) * 8);
        *reinterpret_cast<int4*>(BsmRaw + (size_t)tid * 16) = st0;
        *reinterpret_cast<int4*>(BsmRaw + (size_t)(tid + 576) * 16) = st1;
        if (tid < 384) *reinterpret_cast<int4*>(BsmRaw + (size_t)(tid + 1152) * 16) = st2;
    }
    __syncthreads();

    for (int ni = 0; ni < 16; ++ni) {
        const int n = n0 + ni;
        char* Bcur = BsmRaw + (size_t)(ni & 1) * 24576;
        char* Bnxt = BsmRaw + (size_t)((ni + 1) & 1) * 24576;

        if (ni < 15) {   // issue next caption's loads (latency hidden by MFMA)
            const unsigned short* WF = Wp2F + (size_t)((n + 1) * 16 + g) * 12288;
            st0 = *reinterpret_cast<const int4*>(WF + (size_t)tid * 8);
            st1 = *reinterpret_cast<const int4*>(WF + (size_t)(tid + 576) * 8);
            if (tid < 384) st2 = *reinterpret_cast<const int4*>(WF + (size_t)(tid + 1152) * 8);
        }

        f32x16 acc0 = {}, acc1 = {};
        #pragma unroll
        for (int k = 0; k < 3; ++k) {
            #pragma unroll
            for (int ks = 0; ks < 4; ++ks) {
                const char* fb = Bcur + k * 8192 + ks * 1024 + (size_t)lane * 16;
                const short8 bf0 = *reinterpret_cast<const short8*>(fb);
                const short8 bf1 = *reinterpret_cast<const short8*>(fb + 4096);
                acc0 = __builtin_amdgcn_mfma_f32_32x32x16_bf16(afr[k][ks], bf0, acc0, 0, 0, 0);
                acc1 = __builtin_amdgcn_mfma_f32_32x32x16_bf16(afr[k][ks], bf1, acc1, 0, 0, 0);
            }
        }

        if (ni < 15) {   // write staged B into inactive buffer
            *reinterpret_cast<int4*>(Bnxt + (size_t)tid * 16) = st0;
            *reinterpret_cast<int4*>(Bnxt + (size_t)(tid + 576) * 16) = st1;
            if (tid < 384) *reinterpret_cast<int4*>(Bnxt + (size_t)(tid + 1152) * 16) = st2;
        }

        // epilogue: leaky + per-image column sums -> Sw[ni&1]
        float s0A = 0.f, s0B = 0.f, s1A = 0.f, s1B = 0.f;
        #pragma unroll
        for (int reg = 0; reg < 16; ++reg) {
            const int rit = (reg & 3) + 8 * (reg >> 2) + 4 * khalf;
            const float v0 = leakyf(acc0[reg]);
            const float v1 = leakyf(acc1[reg]);
            if (rit >= bsplit) { s0B += v0; s1B += v1; }
            else               { s0A += v0; s1A += v1; }
        }
        s0A += __shfl_xor(s0A, 32); s0B += __shfl_xor(s0B, 32);
        s1A += __shfl_xor(s1A, 32); s1B += __shfl_xor(s1B, 32);
        const int q = ni & 1;
        if (khalf == 0) {
            Sw[q][wv][0][lrow]      = s0A;
            Sw[q][wv][0][32 + lrow] = s1A;
            if (bsplit < 32) {
                Sw[q][wv][1][lrow]      = s0B;
                Sw[q][wv][1][32 + lrow] = s1B;
            }
        }
        __syncthreads();   // Sw[q] complete; Bnxt staged

        if (tid < 128) {   // gather: img b = waves {b,slot1}+{b+1,slot0} (b>0)
            const int b = tid >> 4, j = tid & 15;
            const float4 ca4 = *reinterpret_cast<const float4*>(&cap_act [n * LATENT + g * CPG + j * 4]);
            const float4 cr4 = *reinterpret_cast<const float4*>(&cap_repr[n * LATENT + g * CPG + j * 4]);
            const float cav[4] = {ca4.x, ca4.y, ca4.z, ca4.w};
            const float crv[4] = {cr4.x, cr4.y, cr4.z, cr4.w};
            float d = 0.f, ss = 0.f;
            #pragma unroll
            for (int u = 0; u < 4; ++u) {
                const int o = j * 4 + u;
                const float S = (b == 0)
                    ? Sw[q][0][0][o] + Sw[q][1][0][o]
                    : Sw[q][b][1][o] + Sw[q][b + 1][0][o];
                const float tmp = S * cav[u];          // cap_act pre-scaled by 1/36
                d = fmaf(tmp, crv[u], d);
                ss = fmaf(tmp, tmp, ss);
            }
            #pragma unroll
            for (int off = 1; off <= 8; off <<= 1) {
                d += __shfl_xor(d, off);
                ss += __shfl_xor(ss, off);
            }
            if (j == 0) {
                part_dot[((size_t)n * BI + b0 + b) * NGROUPS + g] = d;
                part_ss [((size_t)n * BI + b0 + b) * NGROUPS + g] = ss;
            }
        }
    }
}

// ---------------------------------------------------------------------------
// Kernel 4: combine 16 group-partials -> sims[b*32+n]
// ---------------------------------------------------------------------------
__global__ __launch_bounds__(256) void final_kernel(
    const float* __restrict__ part_dot, const float* __restrict__ part_ss,
    const float* __restrict__ norm_capr, float* __restrict__ out)
{
    const int idx = blockIdx.x * 256 + threadIdx.x;   // 4096
    const int n = idx & 31;
    const int b = idx >> 5;
    const size_t base = ((size_t)n * BI + b) * NGROUPS;
    float d = 0.f, s = 0.f;
    #pragma unroll
    for (int g = 0; g < NGROUPS; ++g) { d += part_dot[base + g]; s += part_ss[base + g]; }
    out[b * BC + n] = d / (sqrtf(s) * norm_capr[n]);
}

// ---------------------------------------------------------------------------
extern "C" void kernel_launch(void* const* d_in, const int* in_sizes, int n_in,
                              void* d_out, int out_size, void* d_ws, size_t ws_size,
                              hipStream_t stream) {
    const float* img_embed = (const float*)d_in[0];   // (128, 36, 1024)
    const float* cap_embed = (const float*)d_in[1];   // (32, 50, 1024)
    const int*   lens      = (const int*)  d_in[2];   // (32,)
    const float* red_w     = (const float*)d_in[3];   // (1024, 256)
    const float* red_b     = (const float*)d_in[4];   // (256,)
    const float* proj_w    = (const float*)d_in[5];   // (256, 196608)
    const float* proj_b    = (const float*)d_in[6];   // (196608,)
    float* out = (float*)d_out;                        // (128, 32)

    char* ws = (char*)d_ws;
    unsigned short* Wp2F   = (unsigned short*)(ws);                    // 12,582,912 B
    float* cap_repr  = (float*)(ws + 22020096);                        //    131,072 B
    float* cap_act   = (float*)(ws + 22151168);                        //    131,072 B
    unsigned short* qbfF = (unsigned short*)(ws + 22282240);           //     16,384 B
    float* norm_capr = (float*)(ws + 22315008);                        //        512 B
    float* part_dot  = (float*)(ws + 22315520);                        //    262,144 B
    float* part_ss   = (float*)(ws + 22577664);                        //    262,144 B

    hipLaunchKernelGGL(cap_mean_kernel, dim3(BC), dim3(256), 0, stream,
                       cap_embed, lens, cap_repr, cap_act, norm_capr);
    hipLaunchKernelGGL(q_kernel, dim3(8, BC), dim3(256), 0, stream,
                       cap_repr, red_w, red_b, qbfF);
    hipLaunchKernelGGL(wgen10_kernel, dim3(256), dim3(512), 0, stream,
                       qbfF, proj_w, proj_b, Wp2F);
    hipLaunchKernelGGL(conv5_kernel, dim3(NGROUPS, 16, 2), dim3(576), 0, stream,
                       img_embed, Wp2F, cap_repr, cap_act, part_dot, part_ss);
    hipLaunchKernelGGL(final_kernel, dim3(16), dim3(256), 0, stream,
                       part_dot, part_ss, norm_capr, out);
}